// Round 7
// baseline (1006.173 us; speedup 1.0000x reference)
//
#include <hip/hip_runtime.h>
#include <hip/hip_bf16.h>
#include <stdint.h>

// Pipeline:
//   k_gemm1 : xq[t,u] = float2( relu(s@(Wr-Wi).T+br), relu(s@(Wr+Wi).T+bi) )  [BIT-FROZEN]
//   k_hopf  : sequential Hopf chains; r5 BIT-EXACT arithmetic (range-reduced Taylor
//             + Newton renorm). Both oscillators of a unit merged into one thread:
//             two independent dep-chains interleave -> ~2x per-chain cadence.
//   k_wsplit: W -> (Whi,Wlo) bf16 split planes
//   k_critic: value[t] = |c-linear(d1[t])|
//   k_ld    : lD1/lD2
//   k_gemmD : MFMA 16x16x32 bf16, split weights, K-split x4, dbuf LDS  [validated r6]
//   k_epi   : reduce partials + lD scaling + bias + relu + noise + norm
//   k_scan  : gpi = 0.01*cumsum(nrm), softmax, outputs

#define T_ 4096
#define D_ 256
#define U_ 2048
#define A_ 64

typedef __attribute__((ext_vector_type(8))) short short8;
typedef __attribute__((ext_vector_type(4))) float f32x4;

__device__ __forceinline__ float bflo(uint32_t p) { return __uint_as_float(p << 16); }
__device__ __forceinline__ float bfhi(uint32_t p) { return __uint_as_float(p & 0xffff0000u); }

// ---------------- GEMM1 [UNCHANGED/BIT-FROZEN] ----------------
__global__ __launch_bounds__(256) void k_gemm1(
    const float* __restrict__ S, const float* __restrict__ Wr,
    const float* __restrict__ Wi, const float* __restrict__ br,
    const float* __restrict__ bi, float* __restrict__ xq) {
  __shared__ float sT[32][68];
  __shared__ float wrT[32][68];
  __shared__ float wiT[32][68];
  const int tid = threadIdx.x;
  const int t0 = blockIdx.x * 64;
  const int u0 = blockIdx.y * 64;
  const int un = tid & 15, tm = tid >> 4;
  const int lr = tid >> 3;
  const int lc = (tid & 7) * 4;
  float accR[4][4] = {}, accI[4][4] = {};
  for (int k0 = 0; k0 < D_; k0 += 32) {
    __syncthreads();
#pragma unroll
    for (int p = 0; p < 2; ++p) {
      const int row = p * 32 + lr;
      float4 v = *(const float4*)&S[(size_t)(t0 + row) * D_ + k0 + lc];
      sT[lc + 0][row] = v.x; sT[lc + 1][row] = v.y;
      sT[lc + 2][row] = v.z; sT[lc + 3][row] = v.w;
      float4 a = *(const float4*)&Wr[(size_t)(u0 + row) * D_ + k0 + lc];
      wrT[lc + 0][row] = a.x; wrT[lc + 1][row] = a.y;
      wrT[lc + 2][row] = a.z; wrT[lc + 3][row] = a.w;
      float4 b = *(const float4*)&Wi[(size_t)(u0 + row) * D_ + k0 + lc];
      wiT[lc + 0][row] = b.x; wiT[lc + 1][row] = b.y;
      wiT[lc + 2][row] = b.z; wiT[lc + 3][row] = b.w;
    }
    __syncthreads();
#pragma unroll
    for (int k = 0; k < 32; ++k) {
      const float4 sv = *(const float4*)&sT[k][tm * 4];
      const float4 ar = *(const float4*)&wrT[k][un * 4];
      const float4 ai = *(const float4*)&wiT[k][un * 4];
      const float ss[4] = {sv.x, sv.y, sv.z, sv.w};
      const float wd[4] = {ar.x - ai.x, ar.y - ai.y, ar.z - ai.z, ar.w - ai.w};
      const float wm[4] = {ar.x + ai.x, ar.y + ai.y, ar.z + ai.z, ar.w + ai.w};
#pragma unroll
      for (int i = 0; i < 4; ++i)
#pragma unroll
        for (int j = 0; j < 4; ++j) {
          accR[i][j] = fmaf(ss[i], wd[j], accR[i][j]);
          accI[i][j] = fmaf(ss[i], wm[j], accI[i][j]);
        }
    }
  }
  const float4 brv = *(const float4*)&br[u0 + un * 4];
  const float4 biv = *(const float4*)&bi[u0 + un * 4];
  const float brx[4] = {brv.x, brv.y, brv.z, brv.w};
  const float bix[4] = {biv.x, biv.y, biv.z, biv.w};
#pragma unroll
  for (int i = 0; i < 4; ++i) {
    float vr[4], vi[4];
#pragma unroll
    for (int j = 0; j < 4; ++j) {
      vr[j] = fmaxf(accR[i][j] + brx[j], 0.f);
      vi[j] = fmaxf(accI[i][j] + bix[j], 0.f);
    }
    const size_t base = ((size_t)(t0 + tm * 4 + i) * U_ + u0 + un * 4) * 2;
    *(float4*)&xq[base + 0] = make_float4(vr[0], vi[0], vr[1], vi[1]);
    *(float4*)&xq[base + 4] = make_float4(vr[2], vi[2], vr[3], vi[3]);
  }
}

// ---------------- Hopf chains: r5-exact arithmetic, 2 chains/thread ----------------
// 32 blocks x 64 threads; thread u runs osc1 AND osc2 chains (independent dep
// chains interleave in the latency slots; per-chain FP sequence == r5 bit-exact).
__global__ __launch_bounds__(64) void k_hopf(
    const float* __restrict__ xq, const float* __restrict__ phi1,
    const float* __restrict__ phi2, const float* __restrict__ om1,
    const float* __restrict__ om2, uint32_t* __restrict__ d1c,
    uint32_t* __restrict__ d2c) {
  const int u = blockIdx.x * 64 + threadIdx.x;
  const float S1 = -0.16666667f, S2 = 8.3333333e-3f, S3 = -1.9841270e-4f,
              S4 = 2.7557319e-6f;
  const float C1 = -0.5f, C2 = 4.1666668e-2f, C3 = -1.3888889e-3f,
              C4 = 2.4801587e-5f;
  const float INV2PI = 0.15915494f, N2PI = -6.2831853f;
  const float dto1 = 0.01f * om1[u];
  const float dto2 = 0.01f * om2[u];
  uint32_t* __restrict__ dst1 = d1c + u;
  uint32_t* __restrict__ dst2 = d2c + u;
  const float2* __restrict__ srcQ = ((const float2*)xq) + u;
  float r1 = 1.0f, rinv1 = 1.0f, r2v = 1.0f, rinv2 = 1.0f;
  float c1, s1v, c2, s2v;
  __sincosf(phi1[u] * 0.1f, &s1v, &c1);
  __sincosf(phi2[u] * 0.1f, &s2v, &c2);
  constexpr int PF = 16;
  float2 buf[PF];
#pragma unroll
  for (int i = 0; i < PF; ++i) buf[i] = srcQ[(size_t)i * U_];
  const float2* pre = srcQ + (size_t)PF * U_;  // final-group prefetch overruns
                                               // into d1c region: mapped, unused
  for (int t0 = 0; t0 < T_; t0 += PF) {
#pragma unroll
    for (int i = 0; i < PF; ++i) {
      const float xr = buf[i].x, xi = buf[i].y;
      buf[i] = pre[0];
      pre += U_;
      // ---- chain 1 (bit-exact r5 sequence) ----
      {
        const float f = fmaf(xr, c1, xi * s1v);
        const float g = fmaf(xi, c1, -(xr * s1v));
        const float rn = fmaf(0.01f, fmaf(r1, 1.0f - r1 * r1, f), r1);
        const float dphi = fmaf(0.01f, g * rinv1, dto1);
        const float n = __builtin_rintf(dphi * INV2PI);
        const float t = fmaf(n, N2PI, dphi);
        const float q = t * t;
        const float sp = fmaf(q, fmaf(q, fmaf(q, S4, S3), S2), S1);
        const float sd = t * fmaf(q, sp, 1.0f);
        const float cp = fmaf(q, fmaf(q, fmaf(q, C4, C3), C2), C1);
        const float cd = fmaf(q, cp, 1.0f);
        const float cn0 = fmaf(c1, cd, -(s1v * sd));
        const float sn0 = fmaf(s1v, cd, c1 * sd);
        const float nn = fmaf(cn0, cn0, sn0 * sn0);
        const float h = fmaf(-0.5f, nn, 1.5f);
        const float cn = cn0 * h;
        const float sn = sn0 * h;
        const __hip_bfloat162 pk =
            __float22bfloat162_rn(make_float2(rn * cn, rn * sn));
        uint32_t pw;
        __builtin_memcpy(&pw, &pk, 4);
        dst1[(size_t)(t0 + i) * U_] = pw;
        rinv1 = __builtin_amdgcn_rcpf(fmaxf(rn, 1e-6f));
        r1 = rn; c1 = cn; s1v = sn;
      }
      // ---- chain 2 (bit-exact r5 sequence) ----
      {
        const float f = fmaf(xr, c2, xi * s2v);
        const float g = fmaf(xi, c2, -(xr * s2v));
        const float rn = fmaf(0.01f, fmaf(r2v, 1.0f - r2v * r2v, f), r2v);
        const float dphi = fmaf(0.01f, g * rinv2, dto2);
        const float n = __builtin_rintf(dphi * INV2PI);
        const float t = fmaf(n, N2PI, dphi);
        const float q = t * t;
        const float sp = fmaf(q, fmaf(q, fmaf(q, S4, S3), S2), S1);
        const float sd = t * fmaf(q, sp, 1.0f);
        const float cp = fmaf(q, fmaf(q, fmaf(q, C4, C3), C2), C1);
        const float cd = fmaf(q, cp, 1.0f);
        const float cn0 = fmaf(c2, cd, -(s2v * sd));
        const float sn0 = fmaf(s2v, cd, c2 * sd);
        const float nn = fmaf(cn0, cn0, sn0 * sn0);
        const float h = fmaf(-0.5f, nn, 1.5f);
        const float cn = cn0 * h;
        const float sn = sn0 * h;
        const __hip_bfloat162 pk =
            __float22bfloat162_rn(make_float2(rn * cn, rn * sn));
        uint32_t pw;
        __builtin_memcpy(&pw, &pk, 4);
        dst2[(size_t)(t0 + i) * U_] = pw;
        rinv2 = __builtin_amdgcn_rcpf(fmaxf(rn, 1e-6f));
        r2v = rn; c2 = cn; s2v = sn;
      }
    }
  }
}

// ---------------- Weight split: W -> Whi + Wlo (bf16 planes) ----------------
__global__ __launch_bounds__(256) void k_wsplit(
    const float* __restrict__ dpWr, const float* __restrict__ dpWi,
    const float* __restrict__ ipWr, const float* __restrict__ ipWi,
    uint16_t* __restrict__ wsp) {
  const int g = blockIdx.x * 256 + threadIdx.x;
  const int e0 = g * 4;
  const int mat = e0 >> 17;
  const int off = e0 & 131071;
  const float* W = mat == 0 ? dpWr : mat == 1 ? dpWi : mat == 2 ? ipWr : ipWi;
  const float4 v = *(const float4*)&W[off];
  const float vv[4] = {v.x, v.y, v.z, v.w};
  uint16_t hi[4], lo[4];
#pragma unroll
  for (int j = 0; j < 4; ++j) {
    __hip_bfloat16 h = __float2bfloat16(vv[j]);
    const float hf = __bfloat162float(h);
    __hip_bfloat16 l = __float2bfloat16(vv[j] - hf);
    __builtin_memcpy(&hi[j], &h, 2);
    __builtin_memcpy(&lo[j], &l, 2);
  }
  *(ushort4*)&wsp[(size_t)mat * 131072 + off] =
      make_ushort4(hi[0], hi[1], hi[2], hi[3]);
  *(ushort4*)&wsp[(size_t)(4 + mat) * 131072 + off] =
      make_ushort4(lo[0], lo[1], lo[2], lo[3]);
}

// ---------------- Critic [UNCHANGED] ----------------
__global__ __launch_bounds__(256) void k_critic(
    const uint32_t* __restrict__ d1c, const float* __restrict__ cWr,
    const float* __restrict__ cWi, const float* __restrict__ cbr,
    const float* __restrict__ cbi, float* __restrict__ value) {
  const int t = blockIdx.x;
  const int tid = threadIdx.x;
  float vr = 0.f, vi = 0.f;
#pragma unroll
  for (int i = 0; i < 8; ++i) {
    const int uu = i * 256 + tid;
    const uint32_t p = d1c[(size_t)t * U_ + uu];
    const float dr = bflo(p), di = bfhi(p);
    const float wr = cWr[uu], wi = cWi[uu];
    vr = fmaf(dr, wr, fmaf(-di, wi, vr));
    vi = fmaf(dr, wi, fmaf(di, wr, vi));
  }
#pragma unroll
  for (int o = 32; o >= 1; o >>= 1) {
    vr += __shfl_xor(vr, o);
    vi += __shfl_xor(vi, o);
  }
  __shared__ float red[2][4];
  if ((tid & 63) == 0) { red[0][tid >> 6] = vr; red[1][tid >> 6] = vi; }
  __syncthreads();
  if (tid == 0) {
    const float r0 = red[0][0] + red[0][1] + red[0][2] + red[0][3] + cbr[0];
    const float i0 = red[1][0] + red[1][1] + red[1][2] + red[1][3] + cbi[0];
    value[t] = sqrtf(r0 * r0 + i0 * i0);
  }
}

// ---------------- lD1/lD2 [UNCHANGED] ----------------
__global__ __launch_bounds__(256) void k_ld(const float* __restrict__ value,
                                            float* __restrict__ lD1,
                                            float* __restrict__ lD2) {
  const int t = blockIdx.x * 256 + threadIdx.x;
  const float v = value[t];
  const float pv = (t > 0) ? value[t - 1] : 0.f;
  const float x = 5.0f * (v - pv);
  const float sg = 1.0f / (1.0f + __expf(-x));
  lD1[t] = sg;
  lD2[t] = 1.0f - sg;
}

// ---------------- Phase-D GEMMs via MFMA (split-bf16 weights) [r6, validated] ----------------
__global__ __launch_bounds__(256) void k_gemmD(
    const uint32_t* __restrict__ d1c, const uint32_t* __restrict__ d2c,
    const uint16_t* __restrict__ wsp, float* __restrict__ mpart) {
  __shared__ uint16_t lds[2][8][64][40];
  const int tid = threadIdx.x;
  const int w = tid >> 6;
  const int lane = tid & 63;
  const int n = lane & 15;
  const int quad = lane >> 4;
  const int t0 = blockIdx.x * 64;
  const int ks = blockIdx.y;
  const int kb = ks * 512;
  const uint32_t* d1p = d1c + (size_t)(t0 + w * 16 + n) * U_ + kb + quad * 8;
  const uint32_t* d2p = d2c + (size_t)(t0 + w * 16 + n) * U_ + kb + quad * 8;
  const int sa = lane >> 2;
  const int sg = lane & 3;
  f32x4 acc[4][4];
#pragma unroll
  for (int m = 0; m < 4; ++m)
#pragma unroll
    for (int a = 0; a < 4; ++a) {
      f32x4 z = {0.f, 0.f, 0.f, 0.f};
      acc[m][a] = z;
    }
#pragma unroll
  for (int pp = 0; pp < 2; ++pp) {
    const int p = w * 2 + pp;
#pragma unroll
    for (int sub = 0; sub < 4; ++sub) {
      const int a = sub * 16 + sa;
      const uint4 v =
          *(const uint4*)&wsp[((size_t)p * 64 + a) * 2048 + kb + sg * 8];
      *(uint4*)&lds[0][p][a][sg * 8] = v;
    }
  }
  uint4 c1a = *(const uint4*)d1p, c1b = *(const uint4*)(d1p + 4);
  uint4 c2a = *(const uint4*)d2p, c2b = *(const uint4*)(d2p + 4);
  __syncthreads();

  for (int kcI = 0; kcI < 16; ++kcI) {
    const int cur = kcI & 1;
    const bool more = (kcI + 1) < 16;
    uint4 wreg[8];
    uint4 n1a, n1b, n2a, n2b;
    if (more) {
      const int kn = kb + (kcI + 1) * 32;
#pragma unroll
      for (int pp = 0; pp < 2; ++pp) {
        const int p = w * 2 + pp;
#pragma unroll
        for (int sub = 0; sub < 4; ++sub) {
          const int a = sub * 16 + sa;
          wreg[pp * 4 + sub] =
              *(const uint4*)&wsp[((size_t)p * 64 + a) * 2048 + kn + sg * 8];
        }
      }
      n1a = *(const uint4*)(d1p + 32); n1b = *(const uint4*)(d1p + 36);
      n2a = *(const uint4*)(d2p + 32); n2b = *(const uint4*)(d2p + 36);
    }
    const uint32_t e1[8] = {c1a.x, c1a.y, c1a.z, c1a.w,
                            c1b.x, c1b.y, c1b.z, c1b.w};
    const uint32_t e2[8] = {c2a.x, c2a.y, c2a.z, c2a.w,
                            c2b.x, c2b.y, c2b.z, c2b.w};
    union FR { uint32_t u[4]; short8 v; } f1r, f1i, nf1i, f2r, f2i, nf2i;
#pragma unroll
    for (int j = 0; j < 4; ++j) {
      const uint32_t a0 = e1[2 * j], a1 = e1[2 * j + 1];
      f1r.u[j] = (a0 & 0xFFFFu) | (a1 << 16);
      f1i.u[j] = (a0 >> 16) | (a1 & 0xFFFF0000u);
      nf1i.u[j] = f1i.u[j] ^ 0x80008000u;
      const uint32_t b0 = e2[2 * j], b1 = e2[2 * j + 1];
      f2r.u[j] = (b0 & 0xFFFFu) | (b1 << 16);
      f2i.u[j] = (b0 >> 16) | (b1 & 0xFFFF0000u);
      nf2i.u[j] = f2i.u[j] ^ 0x80008000u;
    }
#pragma unroll
    for (int at = 0; at < 4; ++at) {
      const int arow = at * 16 + n;
      const short8 WrH = *(const short8*)&lds[cur][0][arow][quad * 8];
      const short8 WiH = *(const short8*)&lds[cur][1][arow][quad * 8];
      const short8 IrH = *(const short8*)&lds[cur][2][arow][quad * 8];
      const short8 IiH = *(const short8*)&lds[cur][3][arow][quad * 8];
      const short8 WrL = *(const short8*)&lds[cur][4][arow][quad * 8];
      const short8 WiL = *(const short8*)&lds[cur][5][arow][quad * 8];
      const short8 IrL = *(const short8*)&lds[cur][6][arow][quad * 8];
      const short8 IiL = *(const short8*)&lds[cur][7][arow][quad * 8];
      acc[0][at] = __builtin_amdgcn_mfma_f32_16x16x32_bf16(f1r.v, WrH, acc[0][at], 0, 0, 0);
      acc[0][at] = __builtin_amdgcn_mfma_f32_16x16x32_bf16(f1r.v, WrL, acc[0][at], 0, 0, 0);
      acc[0][at] = __builtin_amdgcn_mfma_f32_16x16x32_bf16(nf1i.v, WiH, acc[0][at], 0, 0, 0);
      acc[0][at] = __builtin_amdgcn_mfma_f32_16x16x32_bf16(nf1i.v, WiL, acc[0][at], 0, 0, 0);
      acc[1][at] = __builtin_amdgcn_mfma_f32_16x16x32_bf16(f1r.v, WiH, acc[1][at], 0, 0, 0);
      acc[1][at] = __builtin_amdgcn_mfma_f32_16x16x32_bf16(f1r.v, WiL, acc[1][at], 0, 0, 0);
      acc[1][at] = __builtin_amdgcn_mfma_f32_16x16x32_bf16(f1i.v, WrH, acc[1][at], 0, 0, 0);
      acc[1][at] = __builtin_amdgcn_mfma_f32_16x16x32_bf16(f1i.v, WrL, acc[1][at], 0, 0, 0);
      acc[2][at] = __builtin_amdgcn_mfma_f32_16x16x32_bf16(f2r.v, IrH, acc[2][at], 0, 0, 0);
      acc[2][at] = __builtin_amdgcn_mfma_f32_16x16x32_bf16(f2r.v, IrL, acc[2][at], 0, 0, 0);
      acc[2][at] = __builtin_amdgcn_mfma_f32_16x16x32_bf16(nf2i.v, IiH, acc[2][at], 0, 0, 0);
      acc[2][at] = __builtin_amdgcn_mfma_f32_16x16x32_bf16(nf2i.v, IiL, acc[2][at], 0, 0, 0);
      acc[3][at] = __builtin_amdgcn_mfma_f32_16x16x32_bf16(f2r.v, IiH, acc[3][at], 0, 0, 0);
      acc[3][at] = __builtin_amdgcn_mfma_f32_16x16x32_bf16(f2r.v, IiL, acc[3][at], 0, 0, 0);
      acc[3][at] = __builtin_amdgcn_mfma_f32_16x16x32_bf16(f2i.v, IrH, acc[3][at], 0, 0, 0);
      acc[3][at] = __builtin_amdgcn_mfma_f32_16x16x32_bf16(f2i.v, IrL, acc[3][at], 0, 0, 0);
    }
    if (more) {
      const int nxt = cur ^ 1;
#pragma unroll
      for (int pp = 0; pp < 2; ++pp) {
        const int p = w * 2 + pp;
#pragma unroll
        for (int sub = 0; sub < 4; ++sub) {
          const int a = sub * 16 + sa;
          *(uint4*)&lds[nxt][p][a][sg * 8] = wreg[pp * 4 + sub];
        }
      }
      c1a = n1a; c1b = n1b; c2a = n2a; c2b = n2b;
      d1p += 32; d2p += 32;
    }
    __syncthreads();
  }
  const size_t MS = (size_t)T_ * A_;
#pragma unroll
  for (int m = 0; m < 4; ++m)
#pragma unroll
    for (int at = 0; at < 4; ++at) {
      float* dst = mpart + (size_t)(m * 4 + ks) * MS +
                   (size_t)(t0 + w * 16 + quad * 4) * A_ + at * 16 + n;
#pragma unroll
      for (int rg = 0; rg < 4; ++rg) dst[(size_t)rg * A_] = acc[m][at][rg];
    }
}

// ---------------- Epilogue [UNCHANGED] ----------------
__global__ __launch_bounds__(256) void k_epi(
    const float* __restrict__ mpart, const float* __restrict__ lD1,
    const float* __restrict__ lD2, const float* __restrict__ noise,
    const float* __restrict__ dpbr, const float* __restrict__ dpbi,
    const float* __restrict__ ipbr, const float* __restrict__ ipbi,
    float* __restrict__ nrm) {
  const size_t MS = (size_t)T_ * A_;
  const int gid = blockIdx.x * 256 + threadIdx.x;
  const size_t e0 = (size_t)gid * 4;
  const int t = (int)(e0 >> 6);
  const int a0 = (int)(e0 & 63);
  float m[4][4];
#pragma unroll
  for (int mi = 0; mi < 4; ++mi) {
    float4 acc = *(const float4*)&mpart[(size_t)(mi * 4 + 0) * MS + e0];
#pragma unroll
    for (int ksi = 1; ksi < 4; ++ksi) {
      const float4 v = *(const float4*)&mpart[(size_t)(mi * 4 + ksi) * MS + e0];
      acc.x += v.x; acc.y += v.y; acc.z += v.z; acc.w += v.w;
    }
    m[mi][0] = acc.x; m[mi][1] = acc.y; m[mi][2] = acc.z; m[mi][3] = acc.w;
  }
  const float l1 = lD1[t], l2 = lD2[t];
  const float4 nzv = *(const float4*)&noise[e0];
  const float nz[4] = {nzv.x, nzv.y, nzv.z, nzv.w};
  const float4 q1 = *(const float4*)&dpbr[a0];
  const float4 q2 = *(const float4*)&dpbi[a0];
  const float4 q3 = *(const float4*)&ipbr[a0];
  const float4 q4 = *(const float4*)&ipbi[a0];
  const float b1r[4] = {q1.x, q1.y, q1.z, q1.w};
  const float b1i[4] = {q2.x, q2.y, q2.z, q2.w};
  const float b2r[4] = {q3.x, q3.y, q3.z, q3.w};
  const float b2i[4] = {q4.x, q4.y, q4.z, q4.w};
  float res[4];
#pragma unroll
  for (int j = 0; j < 4; ++j) {
    const float dpr = fmaxf(fmaf(l1, m[0][j], b1r[j]), 0.f);
    const float dpi = fmaxf(fmaf(l1, m[1][j], b1i[j]), 0.f);
    const float ipr = fmaxf(fmaf(l2, m[2][j], b2r[j]), 0.f);
    const float ipi = fmaxf(fmaf(l2, m[3][j], b2i[j]), 0.f);
    const float nzs = l2 * (2.f * nz[j] - 1.f);
    const float dr = dpr - ipr - nzs;
    const float di = dpi - ipi;
    res[j] = sqrtf(dr * dr + di * di);
  }
  *(float4*)&nrm[e0] = make_float4(res[0], res[1], res[2], res[3]);
}

// ---------------- Scan + softmax + outputs [UNCHANGED] ----------------
__global__ __launch_bounds__(1024) void k_scan(const float* __restrict__ nrm,
                                               const float* __restrict__ value,
                                               float* __restrict__ out) {
  __shared__ float csum[16][64];
  __shared__ float coff[16][64];
  const int tid = threadIdx.x;
  const int a = tid & 63;
  const int c = tid >> 6;
  const int tb = c * 256;
  float r0 = 0.f, r1 = 0.f, r2 = 0.f, r3 = 0.f;
  for (int i = 0; i < 256; i += 4) {
    r0 += nrm[(size_t)(tb + i + 0) * 64 + a];
    r1 += nrm[(size_t)(tb + i + 1) * 64 + a];
    r2 += nrm[(size_t)(tb + i + 2) * 64 + a];
    r3 += nrm[(size_t)(tb + i + 3) * 64 + a];
  }
  csum[c][a] = (r0 + r1) + (r2 + r3);
  __syncthreads();
  if (tid < 64) {
    float acc = 0.f;
#pragma unroll
    for (int cc = 0; cc < 16; ++cc) {
      coff[cc][tid] = acc;
      acc += csum[cc][tid];
    }
    const float g = 0.01f * acc;
    float mx = g;
#pragma unroll
    for (int o = 32; o >= 1; o >>= 1) mx = fmaxf(mx, __shfl_xor(mx, o));
    const float e = __expf(g - mx);
    float sm = e;
#pragma unroll
    for (int o = 32; o >= 1; o >>= 1) sm += __shfl_xor(sm, o);
    out[tid] = e / sm;
    if (tid == 0) out[64] = value[T_ - 1];
  }
  __syncthreads();
  float off = coff[c][a];
  float* o65 = out + 65;
  for (int i = 0; i < 256; i += 4) {
    const float v0 = nrm[(size_t)(tb + i + 0) * 64 + a];
    const float v1 = nrm[(size_t)(tb + i + 1) * 64 + a];
    const float v2 = nrm[(size_t)(tb + i + 2) * 64 + a];
    const float v3 = nrm[(size_t)(tb + i + 3) * 64 + a];
    off += v0;
    o65[(size_t)(tb + i + 0) * 64 + a] = 0.01f * off;
    off += v1;
    o65[(size_t)(tb + i + 1) * 64 + a] = 0.01f * off;
    off += v2;
    o65[(size_t)(tb + i + 2) * 64 + a] = 0.01f * off;
    off += v3;
    o65[(size_t)(tb + i + 3) * 64 + a] = 0.01f * off;
  }
}

extern "C" void kernel_launch(void* const* d_in, const int* in_sizes, int n_in,
                              void* d_out, int out_size, void* d_ws,
                              size_t ws_size, hipStream_t stream) {
  const float* state = (const float*)d_in[0];
  const float* phi1 = (const float*)d_in[1];
  const float* phi2 = (const float*)d_in[2];
  const float* noise = (const float*)d_in[3];
  const float* om1 = (const float*)d_in[4];
  const float* om2 = (const float*)d_in[5];
  const float* l1Wr = (const float*)d_in[6];
  const float* l1Wi = (const float*)d_in[7];
  const float* l1br = (const float*)d_in[8];
  const float* l1bi = (const float*)d_in[9];
  const float* dpWr = (const float*)d_in[10];
  const float* dpWi = (const float*)d_in[11];
  const float* dpbr = (const float*)d_in[12];
  const float* dpbi = (const float*)d_in[13];
  const float* ipWr = (const float*)d_in[14];
  const float* ipWi = (const float*)d_in[15];
  const float* ipbr = (const float*)d_in[16];
  const float* ipbi = (const float*)d_in[17];
  const float* cWr = (const float*)d_in[18];
  const float* cWi = (const float*)d_in[19];
  const float* cbr = (const float*)d_in[20];
  const float* cbi = (const float*)d_in[21];
  float* out = (float*)d_out;

  // Workspace:
  //   [0,64M)    xq (float2)          -- dead after k_hopf
  //   [64M,96M)  d1c ; [96M,128M) d2c
  //   overlay of [0,64M) after k_hopf:
  //     mpart [0,16M) ; nrm [16M,17M) ; value @17M ; lD1/lD2 +16K/+32K ; wsp @20M
  char* ws = (char*)d_ws;
  float* xq = (float*)(ws + (size_t)0);
  uint32_t* d1c = (uint32_t*)(ws + (size_t)67108864);
  uint32_t* d2c = (uint32_t*)(ws + (size_t)100663296);
  float* mpart = (float*)(ws + (size_t)0);
  float* nrm = (float*)(ws + (size_t)16777216);
  float* value = (float*)(ws + (size_t)17825792);
  float* lD1 = (float*)(ws + (size_t)17825792 + 16384);
  float* lD2 = (float*)(ws + (size_t)17825792 + 32768);
  uint16_t* wsp = (uint16_t*)(ws + (size_t)20971520);

  k_gemm1<<<dim3(T_ / 64, U_ / 64), 256, 0, stream>>>(state, l1Wr, l1Wi, l1br,
                                                      l1bi, xq);
  k_hopf<<<32, 64, 0, stream>>>(xq, phi1, phi2, om1, om2, d1c, d2c);
  k_wsplit<<<512, 256, 0, stream>>>(dpWr, dpWi, ipWr, ipWi, wsp);
  k_critic<<<T_, 256, 0, stream>>>(d1c, cWr, cWi, cbr, cbi, value);
  k_ld<<<T_ / 256, 256, 0, stream>>>(value, lD1, lD2);
  k_gemmD<<<dim3(T_ / 64, 4), 256, 0, stream>>>(d1c, d2c, wsp, mpart);
  k_epi<<<256, 256, 0, stream>>>(mpart, lD1, lD2, noise, dpbr, dpbi, ipbr,
                                 ipbi, nrm);
  k_scan<<<1, 1024, 0, stream>>>(nrm, value, out);
}